// Round 4
// baseline (36.595 us; speedup 1.0000x reference)
//
#include <hip/hip_runtime.h>
#include <hip/hip_bf16.h>

// LDS_84104049590333: diagonal linear SSM + short FIR == one causal conv,
// recast as a bf16 MFMA GEMM:
//   out[m][n] = sum_k xb[m][k] * W[n][k],  W[n][k] = K[n-k] (n>=k, else 0)
//   K[d] = sum_s C[s]*Bp[s]*A[s]^d (+ M[d] for d<5)
// k_build: K taps (fp32, d_ws). k_prep: x->bf16 + Toeplitz W (bf16, d_ws).
// k_gemm : 16x32 output tile per wave, fragments direct from L2 (no LDS, no
//          barriers), depth-2 software prefetch, triangular K-skip
//          (kmax = n0+32), heavy columns dispatched first.

#define T_LEN 1024
#define BSZ_N 896
#define S_DIM 256
#define KX_N  5

typedef __attribute__((ext_vector_type(8))) short bf16x8;   // 8 bf16 = 4 VGPR
typedef __attribute__((ext_vector_type(4))) float f32x4;

#define OFF_XB (16 * 1024)          // bf16 x, 896*1024*2 B
#define OFF_BW (2 * 1024 * 1024)    // bf16 W, 1024*1024*2 B

#define MFMA(a, b, c) __builtin_amdgcn_mfma_f32_16x16x32_bf16(a, b, c, 0, 0, 0)

__device__ __forceinline__ ushort f2bf(float f) {   // RNE float->bf16
    unsigned u = __float_as_uint(f);
    return (ushort)((u + 0x7FFFu + ((u >> 16) & 1u)) >> 16);
}

__global__ __launch_bounds__(256)
void k_build(const float* __restrict__ A, const float* __restrict__ Bp,
             const float* __restrict__ C, const float* __restrict__ M,
             float* __restrict__ Kg) {
    const int d = blockIdx.x;          // 0..1023
    const int s = threadIdx.x;         // 0..255
    const float w = C[s] * Bp[s];
    const float ad = exp2f((float)d * log2f(A[s]));   // A in (e^-5, 1]
    float v = w * ad;
#pragma unroll
    for (int off = 1; off < 64; off <<= 1) v += __shfl_xor(v, off, 64);
    __shared__ float part[4];
    const int wave = threadIdx.x >> 6;
    const int lane = threadIdx.x & 63;
    if (lane == 0) part[wave] = v;
    __syncthreads();
    if (threadIdx.x == 0) {
        float r = part[0] + part[1] + part[2] + part[3];
        if (d < KX_N) r += M[d];
        Kg[d] = r;
    }
}

__global__ __launch_bounds__(256)
void k_prep(const float* __restrict__ x, const float* __restrict__ Kg,
            ushort* __restrict__ xb, ushort* __restrict__ bw) {
    const int n = blockIdx.x;          // 0..1023 (row of W; also row of x if <896)
    const int t = threadIdx.x;         // 0..255, handles k = 4t..4t+3
    ushort4 o;
#pragma unroll
    for (int j = 0; j < 4; ++j) {
        const int d = n - (4 * t + j);
        const float f = (d >= 0) ? Kg[d] : 0.f;       // Kg is 4KB, L1-hot
        ((ushort*)&o)[j] = f2bf(f);
    }
    *(ushort4*)(bw + n * T_LEN + 4 * t) = o;
    if (n < BSZ_N) {
        const float4 xv = *(const float4*)(x + n * T_LEN + 4 * t);
        ushort4 xo;
        ((ushort*)&xo)[0] = f2bf(xv.x);
        ((ushort*)&xo)[1] = f2bf(xv.y);
        ((ushort*)&xo)[2] = f2bf(xv.z);
        ((ushort*)&xo)[3] = f2bf(xv.w);
        *(ushort4*)(xb + n * T_LEN + 4 * t) = xo;
    }
}

__global__ __launch_bounds__(256)
void k_gemm(const ushort* __restrict__ xb, const ushort* __restrict__ bw,
            float* __restrict__ out) {
    const int wave = threadIdx.x >> 6;
    const int lane = threadIdx.x & 63;
    const int gw = blockIdx.x * 4 + wave;   // 0..1791 wave-tiles
    const int jn = 31 - (gw & 31);          // n-tile, heavy (large kmax) first
    const int im = gw >> 5;                 // 0..55 m-tile
    const int m0 = im * 16;
    const int n0 = jn * 32;
    const int steps = jn + 1;               // kmax/32 = (n0+32)/32

    const int r  = lane & 15;               // frag row/col
    const int kb = lane >> 4;               // k-chunk 0..3 (8 bf16 each)

    const ushort* ap  = xb + (m0 + r) * T_LEN + kb * 8;
    const ushort* b0p = bw + (n0 + r) * T_LEN + kb * 8;
    const ushort* b1p = b0p + 16 * T_LEN;

    f32x4 acc0 = {0.f, 0.f, 0.f, 0.f};
    f32x4 acc1 = {0.f, 0.f, 0.f, 0.f};

    // depth-2 software pipeline over K-steps of 32
    bf16x8 aC  = *(const bf16x8*)ap;
    bf16x8 b0C = *(const bf16x8*)b0p;
    bf16x8 b1C = *(const bf16x8*)b1p;
    bf16x8 aN = aC, b0N = b0C, b1N = b1C;
    if (steps > 1) {
        aN  = *(const bf16x8*)(ap + 32);
        b0N = *(const bf16x8*)(b0p + 32);
        b1N = *(const bf16x8*)(b1p + 32);
    }
    for (int s = 0; s < steps - 2; ++s) {
        const int kf = 32 * s + 64;
        const bf16x8 aF  = *(const bf16x8*)(ap + kf);
        const bf16x8 b0F = *(const bf16x8*)(b0p + kf);
        const bf16x8 b1F = *(const bf16x8*)(b1p + kf);
        acc0 = MFMA(aC, b0C, acc0);
        acc1 = MFMA(aC, b1C, acc1);
        aC = aN; b0C = b0N; b1C = b1N;
        aN = aF; b0N = b0F; b1N = b1F;
    }
    if (steps > 1) {
        acc0 = MFMA(aC, b0C, acc0);
        acc1 = MFMA(aC, b1C, acc1);
        aC = aN; b0C = b0N; b1C = b1N;
    }
    acc0 = MFMA(aC, b0C, acc0);
    acc1 = MFMA(aC, b1C, acc1);

    // C/D layout (m89): col = lane&15, row = (lane>>4)*4 + reg
    float* op = out + (m0 + kb * 4) * T_LEN + n0 + r;
#pragma unroll
    for (int g = 0; g < 4; ++g) {
        op[g * T_LEN]      = acc0[g];
        op[g * T_LEN + 16] = acc1[g];
    }
}

extern "C" void kernel_launch(void* const* d_in, const int* in_sizes, int n_in,
                              void* d_out, int out_size, void* d_ws, size_t ws_size,
                              hipStream_t stream) {
    const float* x  = (const float*)d_in[0];  // (896,1024,1) fp32
    const float* A  = (const float*)d_in[1];  // (256,)
    const float* Bp = (const float*)d_in[2];  // (1,256)
    const float* C  = (const float*)d_in[3];  // (256,1)
    const float* M  = (const float*)d_in[4];  // (1,1,5)
    // d_in[5] = h0 == 0, folded into the closed form
    float* out = (float*)d_out;               // (896,1024,1) fp32

    float*  Kg = (float*)d_ws;
    ushort* xb = (ushort*)((char*)d_ws + OFF_XB);
    ushort* bw = (ushort*)((char*)d_ws + OFF_BW);

    k_build<<<dim3(T_LEN), dim3(S_DIM), 0, stream>>>(A, Bp, C, M, Kg);
    k_prep <<<dim3(T_LEN), dim3(256),  0, stream>>>(x, Kg, xb, bw);
    k_gemm <<<dim3(448),   dim3(256),  0, stream>>>(xb, bw, out);
}